// Round 6
// baseline (978.585 us; speedup 1.0000x reference)
//
#include <hip/hip_runtime.h>
#include <stdint.h>

// Problem constants
#define T_SEQ 1024
#define B_SZ  16
#define C_IN  1024
#define C_HID 1024
#define M_ROWS (T_SEQ * B_SZ)   // 16384
#define N_COLS (2 * C_HID)      // 2048  (col 2h = Z_h, col 2h+1 = F_h)
#define K_DIM  (2 * C_IN)       // 2048  (k<1024: X[t-1], k>=1024: X[t])

#define NCHUNK 16
#define CLEN   (T_SEQ / NCHUNK) // 64
#define NBH    (B_SZ * C_HID)   // 16384 channels

typedef __attribute__((ext_vector_type(8))) short bf16x8;
typedef __attribute__((ext_vector_type(4))) float f32x4;
typedef unsigned short u16;

#define MFMA __builtin_amdgcn_mfma_f32_16x16x32_bf16

__device__ __forceinline__ u16 f2bf(float f) {
  union { float f; unsigned u; } v; v.f = f;
  unsigned r = v.u + 0x7fffu + ((v.u >> 16) & 1u);  // RNE
  return (u16)(r >> 16);
}
__device__ __forceinline__ float bf2f(unsigned s) {
  union { unsigned u; float f; } v; v.u = s << 16;
  return v.f;
}

// async global->LDS, 16B per lane. LDS dest is wave-uniform base + lane*16.
__device__ __forceinline__ void async_cp16(const u16* g, u16* l) {
  __builtin_amdgcn_global_load_lds(
      (const __attribute__((address_space(1))) unsigned*)(uintptr_t)g,
      (__attribute__((address_space(3))) unsigned*)(uintptr_t)l,
      16, 0, 0);
}

// ---------------------------------------------------------------------------
// Kernel 1 (fused prep): blocks [0,16400) convert X f32->bf16 with one
// leading zero time-step; blocks [16400,24592) repack Wz/Wf -> Wt
// (N=2048,K=2048) bf16 B^T, Z/F interleaved (row 2h = Wz[h], 2h+1 = Wf[h]).
// ---------------------------------------------------------------------------
__global__ __launch_bounds__(256) void k_prep(const float* __restrict__ X,
                                              const float* __restrict__ Wz,
                                              const float* __restrict__ Wf,
                                              u16* __restrict__ Xp,
                                              u16* __restrict__ Wt) {
  int blk = blockIdx.x;
  if (blk < 16400) {
    int i = blk * 256 + threadIdx.x;            // one thread = 4 elems
    const int total4 = (M_ROWS + B_SZ) * C_IN / 4;
    if (i >= total4) return;
    int e = i << 2;
    const int PAD = B_SZ * C_IN;  // 16384
    ushort4 o;
    if (e < PAD) {
      o.x = o.y = o.z = o.w = 0;
    } else {
      float4 v = *reinterpret_cast<const float4*>(X + (e - PAD));
      o.x = f2bf(v.x); o.y = f2bf(v.y); o.z = f2bf(v.z); o.w = f2bf(v.w);
    }
    *reinterpret_cast<ushort4*>(Xp + e) = o;
  } else {
    int i = (blk - 16400) * 256 + threadIdx.x;  // one thread = one (g,h,c)
    if (i >= 2 * 1024 * 1024) return;
    int g  = i >> 20;
    int hc = i & ((1 << 20) - 1);
    int h  = hc >> 10;
    int c  = hc & 1023;
    const float* W = g ? Wf : Wz;
    float2 w = *reinterpret_cast<const float2*>(W + ((size_t)(h << 10) + c) * 2);
    size_t n = ((size_t)h << 1) | (size_t)g;   // interleave Z/F
    Wt[n * K_DIM + c]        = f2bf(w.x);      // k = 0 tap
    Wt[n * K_DIM + 1024 + c] = f2bf(w.y);      // k = 1 tap
  }
}

// ---------------------------------------------------------------------------
// Kernel 2: 256x256-tile bf16 GEMM, SINGLE-buffered 64 KiB LDS -> 2 blocks/CU.
// Per K-tile: stage-all; vmcnt(0)+barrier; 3 read+MFMA phases (lgkm-only, no
// inter-phase barriers -- all LDS writes landed before the tile started);
// barrier (all reads done); stage(t+1); final MFMA cluster on held regs.
// Cross-block overlap on the CU hides the vmcnt/barrier stalls.
// Swizzle, fragment addressing, fragment-blocked epilogue identical to r5
// (verified: 0 bank conflicts, 1.0x write amplification).
// ---------------------------------------------------------------------------
__global__ __launch_bounds__(512, 4) void k_gemm8(const u16* __restrict__ Xp,
                                                  const u16* __restrict__ Wt,
                                                  const float* __restrict__ bz,
                                                  const float* __restrict__ bfv,
                                                  u16* __restrict__ Cb) {
  __shared__ u16 lds[2][2][8192];  // [A=0/B=1][half][128*64] = 64 KiB
  const int tid  = threadIdx.x;
  const int lane = tid & 63;
  const int wid  = tid >> 6;
  const int wr = wid >> 2;        // m-half of this wave
  const int wc = wid & 3;         // n-quarter
  const int lr = lane & 15;

  // T1: XCD-bijective swizzle (512 blocks, 512%8==0), n-fastest within XCD
  int wg = (blockIdx.x & 7) * 64 + (blockIdx.x >> 3);
  const int m0 = (wg >> 3) << 8;
  const int n0 = (wg & 7) << 8;

  // staging per-thread coords: linear LDS byte p -> logical source byte q
  const int p    = tid << 4;
  const int q    = p ^ (((p >> 7) & 7) << 4);   // involution (bits 4-6 vs 7-9)
  const int grow = q >> 7;                      // logical row 0..63 (issue 0)
  const int gcol = (q & 127) >> 1;              // logical col element
  const int ldsw = (tid >> 6) << 9;             // u16 wave base (wid*1KB)

  // ds_read per-thread coords (u16 units), swizzled column offset
  const int rbase = lr << 6;
  int co[2];
#pragma unroll
  for (int ks = 0; ks < 2; ++ks)
    co[ks] = ((((ks << 6) | ((lane >> 4) << 4)) ^ ((lr & 7) << 4)) >> 1);

  auto stage = [&](int kt) {   // stage the whole K-tile (A both halves + B both)
#pragma unroll
    for (int h = 0; h < 2; ++h) {
      const u16* g = Xp + (size_t)(m0 + (h << 7) + grow + ((kt >= 16) ? B_SZ : 0)) * C_IN
                        + ((kt & 15) << 6) + gcol;
      u16* l = &lds[0][h][ldsw];
      async_cp16(g, l);
      async_cp16(g + (size_t)64 * C_IN, l + 4096);
    }
#pragma unroll
    for (int pp = 0; pp < 2; ++pp) {
      const u16* g = Wt + (size_t)(n0 + (pp << 7) + grow) * K_DIM + (kt << 6) + gcol;
      u16* l = &lds[1][pp][ldsw];
      async_cp16(g, l);
      async_cp16(g + (size_t)64 * K_DIM, l + 4096);
    }
  };

  f32x4 acc[8][4] = {};
  bf16x8 a[4][2], b0[2][2], b1[2][2];

  stage(0);

  const u16* pA = &lds[0][wr][0];
  const u16* pB = &lds[1][wc >> 1][(wc & 1) << 12];

  for (int t = 0; t < 32; ++t) {
    asm volatile("s_waitcnt vmcnt(0)" ::: "memory");   // tile t fully in LDS
    __builtin_amdgcn_s_barrier();                      // visible to all waves

    // ---- phase 1: read a(rows 0-63)+b0; mfma Q(0,0)
#pragma unroll
    for (int mi = 0; mi < 4; ++mi)
#pragma unroll
      for (int ks = 0; ks < 2; ++ks)
        a[mi][ks] = *(const bf16x8*)(pA + (mi << 10) + rbase + co[ks]);
#pragma unroll
    for (int ni = 0; ni < 2; ++ni)
#pragma unroll
      for (int ks = 0; ks < 2; ++ks)
        b0[ni][ks] = *(const bf16x8*)(pB + (ni << 10) + rbase + co[ks]);
    asm volatile("s_waitcnt lgkmcnt(0)" ::: "memory");
    __builtin_amdgcn_s_setprio(1);
#pragma unroll
    for (int mi = 0; mi < 4; ++mi)
#pragma unroll
      for (int ni = 0; ni < 2; ++ni)
#pragma unroll
        for (int ks = 0; ks < 2; ++ks)
          acc[mi][ni] = MFMA(a[mi][ks], b0[ni][ks], acc[mi][ni], 0, 0, 0);
    __builtin_amdgcn_s_setprio(0);

    // ---- phase 2: read b1; mfma Q(0,1)
#pragma unroll
    for (int ni = 0; ni < 2; ++ni)
#pragma unroll
      for (int ks = 0; ks < 2; ++ks)
        b1[ni][ks] = *(const bf16x8*)(pB + ((2 + ni) << 10) + rbase + co[ks]);
    asm volatile("s_waitcnt lgkmcnt(0)" ::: "memory");
    __builtin_amdgcn_s_setprio(1);
#pragma unroll
    for (int mi = 0; mi < 4; ++mi)
#pragma unroll
      for (int ni = 0; ni < 2; ++ni)
#pragma unroll
        for (int ks = 0; ks < 2; ++ks)
          acc[mi][2 + ni] = MFMA(a[mi][ks], b1[ni][ks], acc[mi][2 + ni], 0, 0, 0);
    __builtin_amdgcn_s_setprio(0);

    // ---- phase 3: read a(rows 64-127); mfma Q(1,1)
#pragma unroll
    for (int mi = 0; mi < 4; ++mi)
#pragma unroll
      for (int ks = 0; ks < 2; ++ks)
        a[mi][ks] = *(const bf16x8*)(pA + ((4 + mi) << 10) + rbase + co[ks]);
    asm volatile("s_waitcnt lgkmcnt(0)" ::: "memory");
    __builtin_amdgcn_s_setprio(1);
#pragma unroll
    for (int mi = 0; mi < 4; ++mi)
#pragma unroll
      for (int ni = 0; ni < 2; ++ni)
#pragma unroll
        for (int ks = 0; ks < 2; ++ks)
          acc[4 + mi][2 + ni] = MFMA(a[mi][ks], b1[ni][ks], acc[4 + mi][2 + ni], 0, 0, 0);
    __builtin_amdgcn_s_setprio(0);

    // ---- all reads of tile t complete (each wave's lgkm(0) above) -> barrier,
    // then it is safe to let tile t+1's staged writes land.
    __builtin_amdgcn_s_barrier();
    if (t < 31) stage(t + 1);

    // ---- phase 4: mfma Q(1,0) on held regs (a rows 64-127 x b0)
    __builtin_amdgcn_s_setprio(1);
#pragma unroll
    for (int mi = 0; mi < 4; ++mi)
#pragma unroll
      for (int ni = 0; ni < 2; ++ni)
#pragma unroll
        for (int ks = 0; ks < 2; ++ks)
          acc[4 + mi][ni] = MFMA(a[mi][ks], b0[ni][ks], acc[4 + mi][ni], 0, 0, 0);
    __builtin_amdgcn_s_setprio(0);
  }

  // ---- Epilogue: fused bias+activation, fragment-blocked coalesced stores.
  // C/D frag layout: col16 = lane&15, row16 = (lane>>4)*4 + r.
  const int colp = lane & 15;
  const bool isz = (colp & 1) == 0;          // col parity == lane parity
  const float kk = isz ? 1.702f : 1.0f;
  const int hbase = (n0 + (wc << 6) + colp) >> 1;  // + 8*ni
  const int fmb = (m0 >> 4) + (wr << 3);
  const int fnb = (n0 >> 4) + (wc << 2);
#pragma unroll
  for (int ni = 0; ni < 4; ++ni) {
    float bias = isz ? bz[hbase + 8 * ni] : bfv[hbase + 8 * ni];
#pragma unroll
    for (int mi = 0; mi < 8; ++mi) {
      ushort4 o;
#pragma unroll
      for (int r = 0; r < 4; ++r) {
        float v = acc[mi][ni][r] + bias;
        float s = 1.f / (1.f + __expf(-kk * v));
        ((u16*)&o)[r] = f2bf(isz ? v * s : s);  // quick_gelu : sigmoid
      }
      size_t fi = (size_t)(fmb + mi) * 128 + (fnb + ni);
      *reinterpret_cast<ushort4*>(Cb + fi * 256 + (lane << 2)) = o;
    }
  }
}

// ---------------------------------------------------------------------------
// Chunked scan over fragment-blocked Cb.
// For (t, b4, h): one aligned 16B word holds z[r=0..3] then f[r=0..3]
// (r = b&3, b = b4*4+r) at u16 offset t*32768 + (h>>3)*256 + b4*64 + (h&7)*8.
// Pass 1: per (chunk, b4, h): 4-channel affine coeffs (A,B), h_start = 0.
// ---------------------------------------------------------------------------
__global__ __launch_bounds__(256) void k_scan1(const u16* __restrict__ Cb,
                                               float* __restrict__ Ap,
                                               float* __restrict__ Bp) {
  int i = blockIdx.x * 256 + threadIdx.x;  // 65536 = NCHUNK * 4 * 1024
  int h  = i & (C_HID - 1);
  int b4 = (i >> 10) & 3;
  int c  = i >> 12;
  const size_t lane_off = (size_t)(h >> 3) * 256 + b4 * 64 + (h & 7) * 8;
  float hh[4] = {0.f, 0.f, 0.f, 0.f}, P[4] = {1.f, 1.f, 1.f, 1.f};
#pragma unroll 8
  for (int tt = 0; tt < CLEN; ++tt) {
    size_t t = (size_t)c * CLEN + tt;
    uint4 v = *reinterpret_cast<const uint4*>(Cb + t * 32768 + lane_off);
    float z[4] = {bf2f(v.x & 0xffffu), bf2f(v.x >> 16),
                  bf2f(v.y & 0xffffu), bf2f(v.y >> 16)};
    float f[4] = {bf2f(v.z & 0xffffu), bf2f(v.z >> 16),
                  bf2f(v.w & 0xffffu), bf2f(v.w >> 16)};
#pragma unroll
    for (int r = 0; r < 4; ++r) {
      hh[r] += f[r] * (z[r] - hh[r]);
      P[r]  *= (1.f - f[r]);
    }
  }
  *reinterpret_cast<f32x4*>(Ap + (size_t)i * 4) = (f32x4){hh[0], hh[1], hh[2], hh[3]};
  *reinterpret_cast<f32x4*>(Bp + (size_t)i * 4) = (f32x4){P[0], P[1], P[2], P[3]};
}

// Pass 2+3 merged: each thread (c,b4,h) recombines chunks 0..c-1 (<=15 affine
// steps from L2-hot A/B) to get its start state, then re-runs its chunk and
// writes H (+ tail). Loop count c is block-uniform (no divergence).
__global__ __launch_bounds__(256) void k_scan3(const u16* __restrict__ Cb,
                                               const float* __restrict__ Ap,
                                               const float* __restrict__ Bp,
                                               float* __restrict__ out) {
  int i = blockIdx.x * 256 + threadIdx.x;  // 65536
  int h  = i & (C_HID - 1);
  int b4 = (i >> 10) & 3;
  int c  = i >> 12;
  int j  = i & 4095;
  float hh[4] = {0.f, 0.f, 0.f, 0.f};
  for (int cc = 0; cc < c; ++cc) {         // block-uniform trip count
    size_t idx = ((size_t)cc * 4096 + j) * 4;
    f32x4 A = *reinterpret_cast<const f32x4*>(Ap + idx);
    f32x4 B = *reinterpret_cast<const f32x4*>(Bp + idx);
#pragma unroll
    for (int r = 0; r < 4; ++r) hh[r] = A[r] + B[r] * hh[r];
  }
  const size_t lane_off = (size_t)(h >> 3) * 256 + b4 * 64 + (h & 7) * 8;
#pragma unroll 8
  for (int tt = 0; tt < CLEN; ++tt) {
    size_t t = (size_t)c * CLEN + tt;
    uint4 v = *reinterpret_cast<const uint4*>(Cb + t * 32768 + lane_off);
    float z[4] = {bf2f(v.x & 0xffffu), bf2f(v.x >> 16),
                  bf2f(v.y & 0xffffu), bf2f(v.y >> 16)};
    float f[4] = {bf2f(v.z & 0xffffu), bf2f(v.z >> 16),
                  bf2f(v.w & 0xffffu), bf2f(v.w >> 16)};
    float* op = out + t * 16384 + (size_t)b4 * 4096 + h;
#pragma unroll
    for (int r = 0; r < 4; ++r) {
      hh[r] += f[r] * (z[r] - hh[r]);
      op[r * 1024] = hh[r];
    }
  }
  if (c == NCHUNK - 1) {
    float* tp = out + (size_t)M_ROWS * C_HID + (size_t)b4 * 4096 + h;
#pragma unroll
    for (int r = 0; r < 4; ++r) tp[r * 1024] = hh[r];  // H[-1]
  }
}

// ---------------------------------------------------------------------------
extern "C" void kernel_launch(void* const* d_in, const int* in_sizes, int n_in,
                              void* d_out, int out_size, void* d_ws, size_t ws_size,
                              hipStream_t stream) {
  const float* X   = (const float*)d_in[0];
  const float* Wz  = (const float*)d_in[1];
  const float* bz  = (const float*)d_in[2];
  const float* Wf  = (const float*)d_in[3];
  const float* bf_ = (const float*)d_in[4];
  float* out = (float*)d_out;

  // workspace layout (bf16 = u16):
  u16* Xp = (u16*)d_ws;                                 // (16384+16)*1024 u16
  u16* Wt = Xp + (size_t)(M_ROWS + B_SZ) * C_IN;        // 2048*2048 u16
  u16* Cb = Wt + (size_t)N_COLS * K_DIM;                // 16384*2048 u16 (blocked)
  // scan scratch reuses the (dead after GEMM) Xp region: 2 MB << 33 MB
  float* Ap = (float*)Xp;                               // NCHUNK*NBH f32
  float* Bp = Ap + (size_t)NCHUNK * NBH;

  hipLaunchKernelGGL(k_prep, dim3(16400 + 8192), dim3(256), 0, stream,
                     X, Wz, Wf, Xp, Wt);
  hipLaunchKernelGGL(k_gemm8, dim3((M_ROWS / 256) * (N_COLS / 256)), dim3(512), 0,
                     stream, Xp, Wt, bz, bf_, Cb);
  hipLaunchKernelGGL(k_scan1, dim3(256), dim3(256), 0, stream, Cb, Ap, Bp);
  hipLaunchKernelGGL(k_scan3, dim3(256), dim3(256), 0, stream, Cb, Ap, Bp, out);
}

// Round 7
// 299.874 us; speedup vs baseline: 3.2633x; 3.2633x over previous
//
#include <hip/hip_runtime.h>
#include <stdint.h>

// Problem constants
#define T_SEQ 1024
#define B_SZ  16
#define C_IN  1024
#define C_HID 1024
#define M_ROWS (T_SEQ * B_SZ)   // 16384
#define N_COLS (2 * C_HID)      // 2048  (col 2h = Z_h, col 2h+1 = F_h)
#define K_DIM  (2 * C_IN)       // 2048  (k<1024: X[t-1], k>=1024: X[t])

#define NCHUNK 64
#define CLEN   (T_SEQ / NCHUNK) // 16
#define NBH    (B_SZ * C_HID)   // 16384 channels

typedef __attribute__((ext_vector_type(8))) short bf16x8;
typedef __attribute__((ext_vector_type(4))) float f32x4;
typedef unsigned short u16;

#define MFMA __builtin_amdgcn_mfma_f32_16x16x32_bf16

__device__ __forceinline__ u16 f2bf(float f) {
  union { float f; unsigned u; } v; v.f = f;
  unsigned r = v.u + 0x7fffu + ((v.u >> 16) & 1u);  // RNE
  return (u16)(r >> 16);
}
__device__ __forceinline__ float bf2f(unsigned s) {
  union { unsigned u; float f; } v; v.u = s << 16;
  return v.f;
}

// async global->LDS, 16B per lane. LDS dest is wave-uniform base + lane*16.
__device__ __forceinline__ void async_cp16(const u16* g, u16* l) {
  __builtin_amdgcn_global_load_lds(
      (const __attribute__((address_space(1))) unsigned*)(uintptr_t)g,
      (__attribute__((address_space(3))) unsigned*)(uintptr_t)l,
      16, 0, 0);
}

// ---------------------------------------------------------------------------
// Kernel 1 (fused prep): blocks [0,16400) convert X f32->bf16 with one
// leading zero time-step; blocks [16400,24592) repack Wz/Wf -> Wt
// (N=2048,K=2048) bf16 B^T, Z/F interleaved (row 2h = Wz[h], 2h+1 = Wf[h]).
// ---------------------------------------------------------------------------
__global__ __launch_bounds__(256) void k_prep(const float* __restrict__ X,
                                              const float* __restrict__ Wz,
                                              const float* __restrict__ Wf,
                                              u16* __restrict__ Xp,
                                              u16* __restrict__ Wt) {
  int blk = blockIdx.x;
  if (blk < 16400) {
    int i = blk * 256 + threadIdx.x;            // one thread = 4 elems
    const int total4 = (M_ROWS + B_SZ) * C_IN / 4;
    if (i >= total4) return;
    int e = i << 2;
    const int PAD = B_SZ * C_IN;  // 16384
    ushort4 o;
    if (e < PAD) {
      o.x = o.y = o.z = o.w = 0;
    } else {
      float4 v = *reinterpret_cast<const float4*>(X + (e - PAD));
      o.x = f2bf(v.x); o.y = f2bf(v.y); o.z = f2bf(v.z); o.w = f2bf(v.w);
    }
    *reinterpret_cast<ushort4*>(Xp + e) = o;
  } else {
    int i = (blk - 16400) * 256 + threadIdx.x;  // one thread = one (g,h,c)
    if (i >= 2 * 1024 * 1024) return;
    int g  = i >> 20;
    int hc = i & ((1 << 20) - 1);
    int h  = hc >> 10;
    int c  = hc & 1023;
    const float* W = g ? Wf : Wz;
    float2 w = *reinterpret_cast<const float2*>(W + ((size_t)(h << 10) + c) * 2);
    size_t n = ((size_t)h << 1) | (size_t)g;   // interleave Z/F
    Wt[n * K_DIM + c]        = f2bf(w.x);      // k = 0 tap
    Wt[n * K_DIM + 1024 + c] = f2bf(w.y);      // k = 1 tap
  }
}

// ---------------------------------------------------------------------------
// Kernel 2: 256x256-tile 8-phase bf16 GEMM (round-5 verified: 144us, 0 bank
// conflicts, 1.0x write amplification). Double-buffered 128 KiB LDS,
// launch_bounds(512,2) -- unified VGPR+AGPR ~244/thread, 1 block/CU.
// (Round 6 post-mortem: (512,4) caps the unified file at 128 -> acc spills.)
// ---------------------------------------------------------------------------
__global__ __launch_bounds__(512, 2) void k_gemm8(const u16* __restrict__ Xp,
                                                  const u16* __restrict__ Wt,
                                                  const float* __restrict__ bz,
                                                  const float* __restrict__ bfv,
                                                  u16* __restrict__ Cb) {
  __shared__ u16 lds[2][2][2][8192];  // [buf][A=0/B=1][half][128*64] = 128 KiB
  const int tid  = threadIdx.x;
  const int lane = tid & 63;
  const int wid  = tid >> 6;
  const int wr = wid >> 2;        // m-half of this wave
  const int wc = wid & 3;         // n-quarter
  const int lr = lane & 15;

  // T1: XCD-bijective swizzle (512 blocks, 512%8==0), n-fastest within XCD
  int wg = (blockIdx.x & 7) * 64 + (blockIdx.x >> 3);
  const int m0 = (wg >> 3) << 8;
  const int n0 = (wg & 7) << 8;

  // staging per-thread coords: linear LDS byte p -> logical source byte q
  const int p    = tid << 4;
  const int q    = p ^ (((p >> 7) & 7) << 4);   // involution (bits 4-6 vs 7-9)
  const int grow = q >> 7;                      // logical row 0..63 (issue 0)
  const int gcol = (q & 127) >> 1;              // logical col element
  const int ldsw = (tid >> 6) << 9;             // u16 wave base (wid*1KB)

  // ds_read per-thread coords (u16 units), swizzled column offset
  const int rbase = lr << 6;
  int co[2];
#pragma unroll
  for (int ks = 0; ks < 2; ++ks)
    co[ks] = ((((ks << 6) | ((lane >> 4) << 4)) ^ ((lr & 7) << 4)) >> 1);

  auto stage = [&](int j) {   // j = 4*kt + {0:B0,1:B1,2:A0,3:A1}
    int kt = j >> 2, part = j & 3, buf = kt & 1;
    if (part >= 2) {
      int h = part - 2;
      const u16* g = Xp + (size_t)(m0 + (h << 7) + grow + ((kt >= 16) ? B_SZ : 0)) * C_IN
                        + ((kt & 15) << 6) + gcol;
      u16* l = &lds[buf][0][h][ldsw];
      async_cp16(g, l);
      async_cp16(g + (size_t)64 * C_IN, l + 4096);
    } else {
      const u16* g = Wt + (size_t)(n0 + (part << 7) + grow) * K_DIM + (kt << 6) + gcol;
      u16* l = &lds[buf][1][part][ldsw];
      async_cp16(g, l);
      async_cp16(g + (size_t)64 * K_DIM, l + 4096);
    }
  };

  f32x4 acc[8][4] = {};
  bf16x8 a[4][2], b0[2][2], b1[2][2];

  // prologue: tile0 all halves + tile1 B0,B1,A0  (j0..6); tile0 ready at vmcnt(6)
  for (int j = 0; j < 7; ++j) stage(j);
  asm volatile("s_waitcnt vmcnt(6)" ::: "memory");
  __builtin_amdgcn_s_barrier();

#pragma unroll 2
  for (int t = 0; t < 32; ++t) {
    const int buf = t & 1;
    const u16* pA = &lds[buf][0][wr][0];
    const u16* pB = &lds[buf][1][wc >> 1][(wc & 1) << 12];
    const int jb = 4 * t + 7;

    // ---- P1: read a(s=0)+b0; stage; mfma Q(0,0)
#pragma unroll
    for (int mi = 0; mi < 4; ++mi)
#pragma unroll
      for (int ks = 0; ks < 2; ++ks)
        a[mi][ks] = *(const bf16x8*)(pA + (mi << 10) + rbase + co[ks]);
#pragma unroll
    for (int ni = 0; ni < 2; ++ni)
#pragma unroll
      for (int ks = 0; ks < 2; ++ks)
        b0[ni][ks] = *(const bf16x8*)(pB + (ni << 10) + rbase + co[ks]);
    if (jb < 128) stage(jb);
    __builtin_amdgcn_s_barrier();
    asm volatile("s_waitcnt lgkmcnt(0)" ::: "memory");
    __builtin_amdgcn_s_setprio(1);
#pragma unroll
    for (int mi = 0; mi < 4; ++mi)
#pragma unroll
      for (int ni = 0; ni < 2; ++ni)
#pragma unroll
        for (int ks = 0; ks < 2; ++ks)
          acc[mi][ni] = MFMA(a[mi][ks], b0[ni][ks], acc[mi][ni], 0, 0, 0);
    __builtin_amdgcn_s_setprio(0);
    __builtin_amdgcn_s_barrier();

    // ---- P2: read b1; stage; mfma Q(0,1)
#pragma unroll
    for (int ni = 0; ni < 2; ++ni)
#pragma unroll
      for (int ks = 0; ks < 2; ++ks)
        b1[ni][ks] = *(const bf16x8*)(pB + ((2 + ni) << 10) + rbase + co[ks]);
    if (jb + 1 < 128) stage(jb + 1);
    __builtin_amdgcn_s_barrier();
    asm volatile("s_waitcnt lgkmcnt(0)" ::: "memory");
    __builtin_amdgcn_s_setprio(1);
#pragma unroll
    for (int mi = 0; mi < 4; ++mi)
#pragma unroll
      for (int ni = 0; ni < 2; ++ni)
#pragma unroll
        for (int ks = 0; ks < 2; ++ks)
          acc[mi][2 + ni] = MFMA(a[mi][ks], b1[ni][ks], acc[mi][2 + ni], 0, 0, 0);
    __builtin_amdgcn_s_setprio(0);
    __builtin_amdgcn_s_barrier();

    // ---- P3: read a(s=1); stage; mfma Q(1,1)
#pragma unroll
    for (int mi = 0; mi < 4; ++mi)
#pragma unroll
      for (int ks = 0; ks < 2; ++ks)
        a[mi][ks] = *(const bf16x8*)(pA + ((4 + mi) << 10) + rbase + co[ks]);
    if (jb + 2 < 128) stage(jb + 2);
    __builtin_amdgcn_s_barrier();
    asm volatile("s_waitcnt lgkmcnt(0)" ::: "memory");
    __builtin_amdgcn_s_setprio(1);
#pragma unroll
    for (int mi = 0; mi < 4; ++mi)
#pragma unroll
      for (int ni = 0; ni < 2; ++ni)
#pragma unroll
        for (int ks = 0; ks < 2; ++ks)
          acc[4 + mi][2 + ni] = MFMA(a[mi][ks], b1[ni][ks], acc[4 + mi][2 + ni], 0, 0, 0);
    __builtin_amdgcn_s_setprio(0);
    __builtin_amdgcn_s_barrier();

    // ---- P4: no reads (b0 kept in regs); stage; vmcnt; mfma Q(1,0)
    if (jb + 3 < 128) stage(jb + 3);
    if (t < 30) asm volatile("s_waitcnt vmcnt(6)" ::: "memory");
    else        asm volatile("s_waitcnt vmcnt(0)" ::: "memory");
    __builtin_amdgcn_s_barrier();
    __builtin_amdgcn_s_setprio(1);
#pragma unroll
    for (int mi = 0; mi < 4; ++mi)
#pragma unroll
      for (int ni = 0; ni < 2; ++ni)
#pragma unroll
        for (int ks = 0; ks < 2; ++ks)
          acc[4 + mi][ni] = MFMA(a[mi][ks], b0[ni][ks], acc[4 + mi][ni], 0, 0, 0);
    __builtin_amdgcn_s_setprio(0);
    __builtin_amdgcn_s_barrier();
  }

  // ---- Epilogue: fused bias+activation, fragment-blocked coalesced stores.
  // C/D frag layout: col16 = lane&15, row16 = (lane>>4)*4 + r.
  const int colp = lane & 15;
  const bool isz = (colp & 1) == 0;          // col parity == lane parity
  const float kk = isz ? 1.702f : 1.0f;
  const int hbase = (n0 + (wc << 6) + colp) >> 1;  // + 8*ni
  const int fmb = (m0 >> 4) + (wr << 3);
  const int fnb = (n0 >> 4) + (wc << 2);
#pragma unroll
  for (int ni = 0; ni < 4; ++ni) {
    float bias = isz ? bz[hbase + 8 * ni] : bfv[hbase + 8 * ni];
#pragma unroll
    for (int mi = 0; mi < 8; ++mi) {
      ushort4 o;
#pragma unroll
      for (int r = 0; r < 4; ++r) {
        float v = acc[mi][ni][r] + bias;
        float s = 1.f / (1.f + __expf(-kk * v));
        ((u16*)&o)[r] = f2bf(isz ? v * s : s);  // quick_gelu : sigmoid
      }
      size_t fi = (size_t)(fmb + mi) * 128 + (fnb + ni);
      *reinterpret_cast<ushort4*>(Cb + fi * 256 + (lane << 2)) = o;
    }
  }
}

// ---------------------------------------------------------------------------
// Chunked scan over fragment-blocked Cb. NCHUNK=64, CLEN=16:
// 262144 threads (1024 blocks, 4 blocks/CU) -- 4x the TLP of round 5/6,
// serial chains 16 steps instead of 64.
// For (t, b4, h): one aligned 16B word holds z[r=0..3] then f[r=0..3]
// at u16 offset t*32768 + (h>>3)*256 + b4*64 + (h&7)*8.
// Pass 1: per (chunk, b4, h): 4-channel affine coeffs (A,B), h_start = 0.
// ---------------------------------------------------------------------------
__global__ __launch_bounds__(256) void k_scan1(const u16* __restrict__ Cb,
                                               float* __restrict__ Ap,
                                               float* __restrict__ Bp) {
  int i = blockIdx.x * 256 + threadIdx.x;  // 262144 = NCHUNK * 4 * 1024
  int h  = i & (C_HID - 1);
  int b4 = (i >> 10) & 3;
  int c  = i >> 12;
  const size_t lane_off = (size_t)(h >> 3) * 256 + b4 * 64 + (h & 7) * 8;
  float hh[4] = {0.f, 0.f, 0.f, 0.f}, P[4] = {1.f, 1.f, 1.f, 1.f};
#pragma unroll 8
  for (int tt = 0; tt < CLEN; ++tt) {
    size_t t = (size_t)c * CLEN + tt;
    uint4 v = *reinterpret_cast<const uint4*>(Cb + t * 32768 + lane_off);
    float z[4] = {bf2f(v.x & 0xffffu), bf2f(v.x >> 16),
                  bf2f(v.y & 0xffffu), bf2f(v.y >> 16)};
    float f[4] = {bf2f(v.z & 0xffffu), bf2f(v.z >> 16),
                  bf2f(v.w & 0xffffu), bf2f(v.w >> 16)};
#pragma unroll
    for (int r = 0; r < 4; ++r) {
      hh[r] += f[r] * (z[r] - hh[r]);
      P[r]  *= (1.f - f[r]);
    }
  }
  *reinterpret_cast<f32x4*>(Ap + (size_t)i * 4) = (f32x4){hh[0], hh[1], hh[2], hh[3]};
  *reinterpret_cast<f32x4*>(Bp + (size_t)i * 4) = (f32x4){P[0], P[1], P[2], P[3]};
}

// Pass 2+3 merged: each thread (c,b4,h) recombines chunks 0..c-1 (<=63 affine
// steps from L2-hot A/B) to get its start state, then re-runs its chunk and
// writes H (+ tail). Loop count c is block-uniform (no divergence).
__global__ __launch_bounds__(256) void k_scan3(const u16* __restrict__ Cb,
                                               const float* __restrict__ Ap,
                                               const float* __restrict__ Bp,
                                               float* __restrict__ out) {
  int i = blockIdx.x * 256 + threadIdx.x;  // 262144
  int h  = i & (C_HID - 1);
  int b4 = (i >> 10) & 3;
  int c  = i >> 12;
  int j  = i & 4095;
  float hh[4] = {0.f, 0.f, 0.f, 0.f};
  for (int cc = 0; cc < c; ++cc) {         // block-uniform trip count
    size_t idx = ((size_t)cc * 4096 + j) * 4;
    f32x4 A = *reinterpret_cast<const f32x4*>(Ap + idx);
    f32x4 B = *reinterpret_cast<const f32x4*>(Bp + idx);
#pragma unroll
    for (int r = 0; r < 4; ++r) hh[r] = A[r] + B[r] * hh[r];
  }
  const size_t lane_off = (size_t)(h >> 3) * 256 + b4 * 64 + (h & 7) * 8;
#pragma unroll 8
  for (int tt = 0; tt < CLEN; ++tt) {
    size_t t = (size_t)c * CLEN + tt;
    uint4 v = *reinterpret_cast<const uint4*>(Cb + t * 32768 + lane_off);
    float z[4] = {bf2f(v.x & 0xffffu), bf2f(v.x >> 16),
                  bf2f(v.y & 0xffffu), bf2f(v.y >> 16)};
    float f[4] = {bf2f(v.z & 0xffffu), bf2f(v.z >> 16),
                  bf2f(v.w & 0xffffu), bf2f(v.w >> 16)};
    float* op = out + t * 16384 + (size_t)b4 * 4096 + h;
#pragma unroll
    for (int r = 0; r < 4; ++r) {
      hh[r] += f[r] * (z[r] - hh[r]);
      op[r * 1024] = hh[r];
    }
  }
  if (c == NCHUNK - 1) {
    float* tp = out + (size_t)M_ROWS * C_HID + (size_t)b4 * 4096 + h;
#pragma unroll
    for (int r = 0; r < 4; ++r) tp[r * 1024] = hh[r];  // H[-1]
  }
}

// ---------------------------------------------------------------------------
extern "C" void kernel_launch(void* const* d_in, const int* in_sizes, int n_in,
                              void* d_out, int out_size, void* d_ws, size_t ws_size,
                              hipStream_t stream) {
  const float* X   = (const float*)d_in[0];
  const float* Wz  = (const float*)d_in[1];
  const float* bz  = (const float*)d_in[2];
  const float* Wf  = (const float*)d_in[3];
  const float* bf_ = (const float*)d_in[4];
  float* out = (float*)d_out;

  // workspace layout (bf16 = u16):
  u16* Xp = (u16*)d_ws;                                 // (16384+16)*1024 u16
  u16* Wt = Xp + (size_t)(M_ROWS + B_SZ) * C_IN;        // 2048*2048 u16
  u16* Cb = Wt + (size_t)N_COLS * K_DIM;                // 16384*2048 u16 (blocked)
  // scan scratch reuses the (dead after GEMM) Xp region: 8 MB << 33 MB
  float* Ap = (float*)Xp;                               // NCHUNK*NBH f32 = 4 MB
  float* Bp = Ap + (size_t)NCHUNK * NBH;                // 4 MB

  hipLaunchKernelGGL(k_prep, dim3(16400 + 8192), dim3(256), 0, stream,
                     X, Wz, Wf, Xp, Wt);
  hipLaunchKernelGGL(k_gemm8, dim3((M_ROWS / 256) * (N_COLS / 256)), dim3(512), 0,
                     stream, Xp, Wt, bz, bf_, Cb);
  hipLaunchKernelGGL(k_scan1, dim3(NCHUNK * 4096 / 256), dim3(256), 0, stream,
                     Cb, Ap, Bp);
  hipLaunchKernelGGL(k_scan3, dim3(NCHUNK * 4096 / 256), dim3(256), 0, stream,
                     Cb, Ap, Bp, out);
}

// Round 8
// 297.403 us; speedup vs baseline: 3.2904x; 1.0083x over previous
//
#include <hip/hip_runtime.h>
#include <stdint.h>

// Problem constants
#define T_SEQ 1024
#define B_SZ  16
#define C_IN  1024
#define C_HID 1024
#define M_ROWS (T_SEQ * B_SZ)   // 16384
#define N_COLS (2 * C_HID)      // 2048  (col 2h = Z_h, col 2h+1 = F_h)
#define K_DIM  (2 * C_IN)       // 2048  (k<1024: X[t-1], k>=1024: X[t])

#define NCHUNK 64
#define CLEN   (T_SEQ / NCHUNK) // 16 = rows-per-GEMM-block / B_SZ -> 1 chunk/block
#define NBH    (B_SZ * C_HID)   // 16384 channels

typedef __attribute__((ext_vector_type(8))) short bf16x8;
typedef __attribute__((ext_vector_type(4))) float f32x4;
typedef unsigned short u16;

#define MFMA __builtin_amdgcn_mfma_f32_16x16x32_bf16

__device__ __forceinline__ u16 f2bf(float f) {
  union { float f; unsigned u; } v; v.f = f;
  unsigned r = v.u + 0x7fffu + ((v.u >> 16) & 1u);  // RNE
  return (u16)(r >> 16);
}
__device__ __forceinline__ float bf2f(unsigned s) {
  union { unsigned u; float f; } v; v.u = s << 16;
  return v.f;
}

// async global->LDS, 16B per lane. LDS dest is wave-uniform base + lane*16.
__device__ __forceinline__ void async_cp16(const u16* g, u16* l) {
  __builtin_amdgcn_global_load_lds(
      (const __attribute__((address_space(1))) unsigned*)(uintptr_t)g,
      (__attribute__((address_space(3))) unsigned*)(uintptr_t)l,
      16, 0, 0);
}

// ---------------------------------------------------------------------------
// Kernel 1 (fused prep): blocks [0,16400) convert X f32->bf16 with one
// leading zero time-step; blocks [16400,24592) repack Wz/Wf -> Wt
// (N=2048,K=2048) bf16 B^T, Z/F interleaved (row 2h = Wz[h], 2h+1 = Wf[h]).
// ---------------------------------------------------------------------------
__global__ __launch_bounds__(256) void k_prep(const float* __restrict__ X,
                                              const float* __restrict__ Wz,
                                              const float* __restrict__ Wf,
                                              u16* __restrict__ Xp,
                                              u16* __restrict__ Wt) {
  int blk = blockIdx.x;
  if (blk < 16400) {
    int i = blk * 256 + threadIdx.x;            // one thread = 4 elems
    const int total4 = (M_ROWS + B_SZ) * C_IN / 4;
    if (i >= total4) return;
    int e = i << 2;
    const int PAD = B_SZ * C_IN;  // 16384
    ushort4 o;
    if (e < PAD) {
      o.x = o.y = o.z = o.w = 0;
    } else {
      float4 v = *reinterpret_cast<const float4*>(X + (e - PAD));
      o.x = f2bf(v.x); o.y = f2bf(v.y); o.z = f2bf(v.z); o.w = f2bf(v.w);
    }
    *reinterpret_cast<ushort4*>(Xp + e) = o;
  } else {
    int i = (blk - 16400) * 256 + threadIdx.x;  // one thread = one (g,h,c)
    if (i >= 2 * 1024 * 1024) return;
    int g  = i >> 20;
    int hc = i & ((1 << 20) - 1);
    int h  = hc >> 10;
    int c  = hc & 1023;
    const float* W = g ? Wf : Wz;
    float2 w = *reinterpret_cast<const float2*>(W + ((size_t)(h << 10) + c) * 2);
    size_t n = ((size_t)h << 1) | (size_t)g;   // interleave Z/F
    Wt[n * K_DIM + c]        = f2bf(w.x);      // k = 0 tap
    Wt[n * K_DIM + 1024 + c] = f2bf(w.y);      // k = 1 tap
  }
}

// ---------------------------------------------------------------------------
// Kernel 2: 256x256-tile 8-phase bf16 GEMM. K-loop byte-identical to the
// round-5/7 verified code (0 bank conflicts, 1.0x write amplification).
// NEW epilogue: activation + in-register 16-step chunk scan (scan pass 1
// fused). Cb word (16B per (t,b4,h)) now stores 4x packed u32:
//   w[r] = bf16(Hpart) | bf16(Ppre)<<16,  where h_t(h0) = Hpart_t + Ppre_t*h0
// Chunk c = m0>>8 (one chunk per block). wr0 owns t%16 in 0..7, wr1 in 8..15;
// wr0 passes its per-channel end state (A0,B0) to wr1 via 16KB of the dead
// staging LDS; wr1 rebases its trajectory: Hp' = hp + pp*A0, Pp' = pp*B0.
// Chunk-level (A,B) = the word at t = 16c+15 (no separate array; avoids any
// write-while-read race with Xp/Wt).
// ---------------------------------------------------------------------------
__global__ __launch_bounds__(512, 2) void k_gemm8(const u16* __restrict__ Xp,
                                                  const u16* __restrict__ Wt,
                                                  const float* __restrict__ bz,
                                                  const float* __restrict__ bfv,
                                                  u16* __restrict__ Cb) {
  __shared__ u16 lds[2][2][2][8192];  // [buf][A=0/B=1][half][128*64] = 128 KiB
  const int tid  = threadIdx.x;
  const int lane = tid & 63;
  const int wid  = tid >> 6;
  const int wr = wid >> 2;        // m-half of this wave
  const int wc = wid & 3;         // n-quarter
  const int lr = lane & 15;

  // T1: XCD-bijective swizzle (512 blocks, 512%8==0), n-fastest within XCD
  int wg = (blockIdx.x & 7) * 64 + (blockIdx.x >> 3);
  const int m0 = (wg >> 3) << 8;
  const int n0 = (wg & 7) << 8;

  // staging per-thread coords: linear LDS byte p -> logical source byte q
  const int p    = tid << 4;
  const int q    = p ^ (((p >> 7) & 7) << 4);   // involution (bits 4-6 vs 7-9)
  const int grow = q >> 7;                      // logical row 0..63 (issue 0)
  const int gcol = (q & 127) >> 1;              // logical col element
  const int ldsw = (tid >> 6) << 9;             // u16 wave base (wid*1KB)

  // ds_read per-thread coords (u16 units), swizzled column offset
  const int rbase = lr << 6;
  int co[2];
#pragma unroll
  for (int ks = 0; ks < 2; ++ks)
    co[ks] = ((((ks << 6) | ((lane >> 4) << 4)) ^ ((lr & 7) << 4)) >> 1);

  auto stage = [&](int j) {   // j = 4*kt + {0:B0,1:B1,2:A0,3:A1}
    int kt = j >> 2, part = j & 3, buf = kt & 1;
    if (part >= 2) {
      int h = part - 2;
      const u16* g = Xp + (size_t)(m0 + (h << 7) + grow + ((kt >= 16) ? B_SZ : 0)) * C_IN
                        + ((kt & 15) << 6) + gcol;
      u16* l = &lds[buf][0][h][ldsw];
      async_cp16(g, l);
      async_cp16(g + (size_t)64 * C_IN, l + 4096);
    } else {
      const u16* g = Wt + (size_t)(n0 + (part << 7) + grow) * K_DIM + (kt << 6) + gcol;
      u16* l = &lds[buf][1][part][ldsw];
      async_cp16(g, l);
      async_cp16(g + (size_t)64 * K_DIM, l + 4096);
    }
  };

  f32x4 acc[8][4] = {};
  bf16x8 a[4][2], b0[2][2], b1[2][2];

  // prologue: tile0 all halves + tile1 B0,B1,A0  (j0..6); tile0 ready at vmcnt(6)
  for (int j = 0; j < 7; ++j) stage(j);
  asm volatile("s_waitcnt vmcnt(6)" ::: "memory");
  __builtin_amdgcn_s_barrier();

#pragma unroll 2
  for (int t = 0; t < 32; ++t) {
    const int buf = t & 1;
    const u16* pA = &lds[buf][0][wr][0];
    const u16* pB = &lds[buf][1][wc >> 1][(wc & 1) << 12];
    const int jb = 4 * t + 7;

    // ---- P1: read a(s=0)+b0; stage; mfma Q(0,0)
#pragma unroll
    for (int mi = 0; mi < 4; ++mi)
#pragma unroll
      for (int ks = 0; ks < 2; ++ks)
        a[mi][ks] = *(const bf16x8*)(pA + (mi << 10) + rbase + co[ks]);
#pragma unroll
    for (int ni = 0; ni < 2; ++ni)
#pragma unroll
      for (int ks = 0; ks < 2; ++ks)
        b0[ni][ks] = *(const bf16x8*)(pB + (ni << 10) + rbase + co[ks]);
    if (jb < 128) stage(jb);
    __builtin_amdgcn_s_barrier();
    asm volatile("s_waitcnt lgkmcnt(0)" ::: "memory");
    __builtin_amdgcn_s_setprio(1);
#pragma unroll
    for (int mi = 0; mi < 4; ++mi)
#pragma unroll
      for (int ni = 0; ni < 2; ++ni)
#pragma unroll
        for (int ks = 0; ks < 2; ++ks)
          acc[mi][ni] = MFMA(a[mi][ks], b0[ni][ks], acc[mi][ni], 0, 0, 0);
    __builtin_amdgcn_s_setprio(0);
    __builtin_amdgcn_s_barrier();

    // ---- P2: read b1; stage; mfma Q(0,1)
#pragma unroll
    for (int ni = 0; ni < 2; ++ni)
#pragma unroll
      for (int ks = 0; ks < 2; ++ks)
        b1[ni][ks] = *(const bf16x8*)(pB + ((2 + ni) << 10) + rbase + co[ks]);
    if (jb + 1 < 128) stage(jb + 1);
    __builtin_amdgcn_s_barrier();
    asm volatile("s_waitcnt lgkmcnt(0)" ::: "memory");
    __builtin_amdgcn_s_setprio(1);
#pragma unroll
    for (int mi = 0; mi < 4; ++mi)
#pragma unroll
      for (int ni = 0; ni < 2; ++ni)
#pragma unroll
        for (int ks = 0; ks < 2; ++ks)
          acc[mi][2 + ni] = MFMA(a[mi][ks], b1[ni][ks], acc[mi][2 + ni], 0, 0, 0);
    __builtin_amdgcn_s_setprio(0);
    __builtin_amdgcn_s_barrier();

    // ---- P3: read a(s=1); stage; mfma Q(1,1)
#pragma unroll
    for (int mi = 0; mi < 4; ++mi)
#pragma unroll
      for (int ks = 0; ks < 2; ++ks)
        a[mi][ks] = *(const bf16x8*)(pA + ((4 + mi) << 10) + rbase + co[ks]);
    if (jb + 2 < 128) stage(jb + 2);
    __builtin_amdgcn_s_barrier();
    asm volatile("s_waitcnt lgkmcnt(0)" ::: "memory");
    __builtin_amdgcn_s_setprio(1);
#pragma unroll
    for (int mi = 0; mi < 4; ++mi)
#pragma unroll
      for (int ni = 0; ni < 2; ++ni)
#pragma unroll
        for (int ks = 0; ks < 2; ++ks)
          acc[4 + mi][2 + ni] = MFMA(a[mi][ks], b1[ni][ks], acc[4 + mi][2 + ni], 0, 0, 0);
    __builtin_amdgcn_s_setprio(0);
    __builtin_amdgcn_s_barrier();

    // ---- P4: no reads (b0 kept in regs); stage; vmcnt; mfma Q(1,0)
    if (jb + 3 < 128) stage(jb + 3);
    if (t < 30) asm volatile("s_waitcnt vmcnt(6)" ::: "memory");
    else        asm volatile("s_waitcnt vmcnt(0)" ::: "memory");
    __builtin_amdgcn_s_barrier();
    __builtin_amdgcn_s_setprio(1);
#pragma unroll
    for (int mi = 0; mi < 4; ++mi)
#pragma unroll
      for (int ni = 0; ni < 2; ++ni)
#pragma unroll
        for (int ks = 0; ks < 2; ++ks)
          acc[4 + mi][ni] = MFMA(a[mi][ks], b0[ni][ks], acc[4 + mi][ni], 0, 0, 0);
    __builtin_amdgcn_s_setprio(0);
    __builtin_amdgcn_s_barrier();
  }

  // ---- Epilogue: activation + fused 16-step chunk scan + packed stores.
  // C/D frag: col16 = lane&15, row16 = (lane>>4)*4 + r  ->  t = frag-row,
  // b = row16, channel h = n>>1, z/f split by lane parity.
  const int colp = lane & 15;
  const bool isz = (colp & 1) == 0;
  const float kk = isz ? 1.702f : 1.0f;
  const int jj = colp >> 1;               // h & 7
  const int b4 = lane >> 4;               // b >> 2
  const int hbase = ((n0 + (wc << 6)) >> 1) + jj;   // + 8*ni
  const int c    = m0 >> 8;               // chunk id
  const int nfb  = (n0 >> 4) + (wc << 2); // frag-col base, + ni
  float* exA = (float*)&lds[0][0][0][0];  // 8 KB, reuse dead staging LDS
  float* exB = exA + 2048;                // 8 KB

  uint4 trj[8];                           // wr1: stash local trajectory per ni
#pragma unroll
  for (int ni = 0; ni < 4; ++ni) {
    float bias = isz ? bz[hbase + 8 * ni] : bfv[hbase + 8 * ni];
    float hh[4] = {0.f, 0.f, 0.f, 0.f}, P[4] = {1.f, 1.f, 1.f, 1.f};
#pragma unroll
    for (int mi = 0; mi < 8; ++mi) {
      unsigned tw[4];
#pragma unroll
      for (int r = 0; r < 4; ++r) {
        float v = acc[mi][ni][r] + bias;
        float s = 1.f / (1.f + __expf(-kk * v));
        float act = isz ? v * s : s;            // quick_gelu : sigmoid
        float par = __shfl_xor(act, 1, 64);     // partner value (f<->z)
        float z = isz ? act : par;
        float f = isz ? par : act;
        hh[r] += f * (z - hh[r]);
        P[r]  *= (1.f - f);
        tw[r] = (unsigned)f2bf(hh[r]) | ((unsigned)f2bf(P[r]) << 16);
      }
      if (wr == 0) {
        if (!(lane & 1)) {
          size_t fi = (size_t)((c << 4) + mi) * 128 + nfb + ni;
          uint4 o; o.x = tw[0]; o.y = tw[1]; o.z = tw[2]; o.w = tw[3];
          *reinterpret_cast<uint4*>(Cb + fi * 256 + (b4 << 6) + (jj << 3)) = o;
        }
      } else {
        uint4 o; o.x = tw[0]; o.y = tw[1]; o.z = tw[2]; o.w = tw[3];
        trj[mi] = o;
      }
    }
    // exchange slot (per ni -> distinct, no WAR across ni iterations)
    const int xi = (((((wc << 2) | b4) << 3) | jj) << 2 | ni) << 2;  // + r
    if (wr == 0 && !(lane & 1)) {
#pragma unroll
      for (int r = 0; r < 4; ++r) { exA[xi + r] = hh[r]; exB[xi + r] = P[r]; }
    }
    __syncthreads();
    if (wr == 1 && !(lane & 1)) {
      float A0[4], B0[4];
#pragma unroll
      for (int r = 0; r < 4; ++r) { A0[r] = exA[xi + r]; B0[r] = exB[xi + r]; }
#pragma unroll
      for (int mi = 0; mi < 8; ++mi) {
        uint4 o;
        unsigned* ow = &o.x;
        const unsigned* iw = &trj[mi].x;
#pragma unroll
        for (int r = 0; r < 4; ++r) {
          float hp = bf2f(iw[r] & 0xffffu);
          float pp = bf2f(iw[r] >> 16);
          float H2 = hp + pp * A0[r];           // rebase onto wr0 end state
          float P2 = pp * B0[r];
          ow[r] = (unsigned)f2bf(H2) | ((unsigned)f2bf(P2) << 16);
        }
        size_t fi = (size_t)((c << 4) + 8 + mi) * 128 + nfb + ni;
        *reinterpret_cast<uint4*>(Cb + fi * 256 + (b4 << 6) + (jj << 3)) = o;
      }
    }
  }
}

// ---------------------------------------------------------------------------
// Kernel 3: final scan pass. Per (c,b4,h): recombine chunk-end words
// (t = 16cc+15 holds the chunk's (A,B)) for cc<c -- L2/L3-hot, <=63 steps --
// then a chain-free elementwise pass: out[t] = Hp_t + Pp_t * h_start.
// ---------------------------------------------------------------------------
__global__ __launch_bounds__(256) void k_scan(const u16* __restrict__ Cb,
                                              float* __restrict__ out) {
  int i = blockIdx.x * 256 + threadIdx.x;  // 262144 = NCHUNK * 4 * 1024
  int h  = i & (C_HID - 1);
  int b4 = (i >> 10) & 3;
  int c  = i >> 12;                        // block-uniform
  const size_t lane_off = (size_t)(h >> 3) * 256 + b4 * 64 + (h & 7) * 8;
  float hh[4] = {0.f, 0.f, 0.f, 0.f};
  for (int cc = 0; cc < c; ++cc) {
    uint4 w = *reinterpret_cast<const uint4*>(
        Cb + ((size_t)cc * CLEN + CLEN - 1) * 32768 + lane_off);
    const unsigned* ww = &w.x;
#pragma unroll
    for (int r = 0; r < 4; ++r) {
      float A = bf2f(ww[r] & 0xffffu), B = bf2f(ww[r] >> 16);
      hh[r] = A + B * hh[r];
    }
  }
#pragma unroll 4
  for (int tt = 0; tt < CLEN; ++tt) {
    size_t t = (size_t)c * CLEN + tt;
    uint4 w = *reinterpret_cast<const uint4*>(Cb + t * 32768 + lane_off);
    const unsigned* ww = &w.x;
    float* op = out + t * 16384 + (size_t)b4 * 4096 + h;
#pragma unroll
    for (int r = 0; r < 4; ++r) {
      float v = bf2f(ww[r] & 0xffffu) + bf2f(ww[r] >> 16) * hh[r];
      op[r * 1024] = v;
      if (c == NCHUNK - 1 && tt == CLEN - 1)
        out[(size_t)M_ROWS * C_HID + (size_t)b4 * 4096 + h + r * 1024] = v;  // H[-1]
    }
  }
}

// ---------------------------------------------------------------------------
extern "C" void kernel_launch(void* const* d_in, const int* in_sizes, int n_in,
                              void* d_out, int out_size, void* d_ws, size_t ws_size,
                              hipStream_t stream) {
  const float* X   = (const float*)d_in[0];
  const float* Wz  = (const float*)d_in[1];
  const float* bz  = (const float*)d_in[2];
  const float* Wf  = (const float*)d_in[3];
  const float* bf_ = (const float*)d_in[4];
  float* out = (float*)d_out;

  // workspace layout (bf16 = u16):
  u16* Xp = (u16*)d_ws;                                 // (16384+16)*1024 u16
  u16* Wt = Xp + (size_t)(M_ROWS + B_SZ) * C_IN;        // 2048*2048 u16
  u16* Cb = Wt + (size_t)N_COLS * K_DIM;                // 16384*2048 u16 (blocked)

  hipLaunchKernelGGL(k_prep, dim3(16400 + 8192), dim3(256), 0, stream,
                     X, Wz, Wf, Xp, Wt);
  hipLaunchKernelGGL(k_gemm8, dim3((M_ROWS / 256) * (N_COLS / 256)), dim3(512), 0,
                     stream, Xp, Wt, bz, bf_, Cb);
  hipLaunchKernelGGL(k_scan, dim3(NCHUNK * 4096 / 256), dim3(256), 0, stream,
                     Cb, out);
}